// Round 1
// baseline (847.392 us; speedup 1.0000x reference)
//
#include <hip/hip_runtime.h>
#include <math.h>

// DTW over M x N grid, single workgroup wavefront over anti-diagonals.
// 256 threads * 8 columns each = 2048 columns. All DP state in registers;
// one float2 LDS exchange + one barrier per diagonal (double-buffered).

#define MM 2048
#define NN 2048
#define CC 8
#define NT 256   // NN / CC
#define INFV 1e30f

__launch_bounds__(NT, 1)
__global__ void dtw_kernel(const float* __restrict__ src,
                           const float* __restrict__ tgt,
                           float* __restrict__ out)
{
    __shared__ float  s_src[MM];
    __shared__ float2 ex[2][NT];

    const int tid = threadIdx.x;

    // stage source into LDS (coalesced)
    #pragma unroll
    for (int k = 0; k < MM / NT; ++k)
        s_src[tid + k * NT] = src[tid + k * NT];

    // this thread's target values, columns j = tid*CC+1 .. tid*CC+CC (1-indexed)
    float tg[CC];
    #pragma unroll
    for (int k = 0; k < CC; ++k)
        tg[k] = tgt[tid * CC + k];

    // DP state: curA/curB ping-pong as (t-1)/(t-2) rows along the diagonal.
    // s[] = source shift register (cell k uses source index t-2-k-(base-1)).
    float curA[CC], curB[CC], s[CC];
    #pragma unroll
    for (int k = 0; k < CC; ++k) { curA[k] = INFV; curB[k] = INFV; s[k] = 0.0f; }

    // diag value for cell 0 = neighbor boundary at t-2 (prev iteration's nb.x).
    // At t=2 this must be D[0][base-1]: 0 for tid 0 (D[0][0]), INF otherwise.
    float nbD_old = (tid == 0) ? 0.0f : INFV;
    const int base = tid * CC + 1;  // 1-indexed column of cell 0

    __syncthreads();

    // One phase = one anti-diagonal t. P holds values at t-1, Q at t-2;
    // new values (at t) overwrite Q. Descending k order makes the in-place
    // shift of s[] and read-before-write of Q[k-1] safe.
#define PHASE(P, Q, T)                                                   \
    {                                                                    \
        const int t_ = (T);                                              \
        float2 w; w.x = P[CC-1]; w.y = s[CC-1];                          \
        ex[t_ & 1][tid] = w;                                             \
        __syncthreads();                                                 \
        float2 nb;                                                       \
        if (tid == 0) {                                                  \
            int si = t_ - 2; if (si > MM - 1) si = MM - 1;               \
            nb.x = INFV; nb.y = s_src[si];                               \
        } else {                                                         \
            nb = ex[t_ & 1][tid - 1];                                    \
        }                                                                \
        const int i0 = t_ - base;                                        \
        _Pragma("unroll")                                                \
        for (int k = CC - 1; k >= 0; --k) {                              \
            float sk   = k ? s[k-1] : nb.y;                              \
            float left = k ? P[k-1] : nb.x;                              \
            float diag = k ? Q[k-1] : nbD_old;                           \
            float up   = P[k];                                           \
            s[k] = sk;                                                   \
            float dd = sk - tg[k];                                       \
            float m  = fminf(fminf(up, left), diag);                     \
            float v  = dd * dd + m;                                      \
            unsigned ii = (unsigned)(i0 - k - 1);                        \
            Q[k] = (ii < (unsigned)MM) ? v : INFV;                       \
        }                                                                \
        nbD_old = nb.x;                                                  \
    }

    // t = 2 .. M+N (4095 diagonals). Run an even count (extra phase at
    // t = M+N+1 computes only invalid cells -> harmless INFs into curA).
    for (int t = 2; t <= MM + NN; t += 2) {
        PHASE(curA, curB, t)
        PHASE(curB, curA, t + 1)
    }
#undef PHASE

    // D[M][N] was computed at t = M+N into curB (cell CC-1 of last thread).
    if (tid == NT - 1)
        out[0] = sqrtf(curB[CC - 1]);
}

extern "C" void kernel_launch(void* const* d_in, const int* in_sizes, int n_in,
                              void* d_out, int out_size, void* d_ws, size_t ws_size,
                              hipStream_t stream)
{
    (void)in_sizes; (void)n_in; (void)out_size; (void)d_ws; (void)ws_size;
    const float* source = (const float*)d_in[0];
    const float* target = (const float*)d_in[1];
    float* out = (float*)d_out;
    dtw_kernel<<<1, NT, 0, stream>>>(source, target, out);
}

// Round 2
// 280.553 us; speedup vs baseline: 3.0204x; 3.0204x over previous
//
#include <hip/hip_runtime.h>
#include <math.h>

// DTW 2048x2048, single workgroup, 8x8 block wavefront.
// 256 threads; thread tid owns columns [tid*8+1 .. tid*8+8] (1-indexed DP).
// Phase p: thread tid computes row-block bi = p - tid (8 rows).
// Up/diag boundary lives in registers (cur[] = bottom row of previous block).
// Left boundary (8 floats) exchanged via double-buffered LDS, one barrier/phase.
// 511 phases total vs 4094 cell-diagonals in R1.

#define MM 2048
#define NN 2048
#define BR 8
#define BC 8
#define NT 256           // NN / BC
#define NB (MM / BR)     // 256 row blocks
#define NPH (NB + NT - 1) // 511 phases
#define EXW 9            // padded stride (floats) -> conflict-free lane access
#define SW 9
#define INFV 1e30f

__launch_bounds__(NT, 1)
__global__ void dtw_kernel(const float* __restrict__ src,
                           const float* __restrict__ tgt,
                           float* __restrict__ out)
{
    __shared__ float s_pad[NB * SW];     // src padded: i -> (i/8)*9 + (i&7)
    __shared__ float ex[2][NT * EXW];    // right-column exchange, double buffered

    const int tid = threadIdx.x;

    for (int i = tid; i < MM; i += NT)
        s_pad[(i >> 3) * SW + (i & 7)] = src[i];

    float tg[BC];
    #pragma unroll
    for (int k = 0; k < BC; ++k) tg[k] = tgt[tid * BC + k];

    // cur[] = D[i_prev_block_bottom][own cols]; init = row 0 boundary (INF, j>=1)
    float cur[BC];
    #pragma unroll
    for (int k = 0; k < BC; ++k) cur[k] = INFV;

    // corner = D[bi*8][tid*8]; at bi=0: D[0][0]=0 for tid 0, else INF
    float corner = (tid == 0) ? 0.0f : INFV;

    __syncthreads();

    for (int p = 0; p < NPH; ++p) {
        const int bi = p - tid;
        if (0 <= bi && bi < NB) {
            // left boundary: D[bi*8+1 .. bi*8+8][tid*8]
            float lc[BR];
            if (tid > 0) {
                const float* e = &ex[(p + 1) & 1][(tid - 1) * EXW];
                #pragma unroll
                for (int r = 0; r < BR; ++r) lc[r] = e[r];
            } else {
                #pragma unroll
                for (int r = 0; r < BR; ++r) lc[r] = INFV;
            }
            const float* sp = &s_pad[bi * SW];
            float srow[BR];
            #pragma unroll
            for (int r = 0; r < BR; ++r) srow[r] = sp[r];

            float rc[BR];
            float dl = corner;  // D[i-1][tid*8] for first row
            #pragma unroll
            for (int r = 0; r < BR; ++r) {
                float l  = lc[r];     // D[i][tid*8]
                float sv = srow[r];
                float dgk = dl;       // D[i-1][j-1] for k=0
                #pragma unroll
                for (int k = 0; k < BC; ++k) {
                    float up = cur[k];                    // D[i-1][j]
                    float m  = fminf(fminf(up, l), dgk);  // -> v_min3_f32
                    float d  = sv - tg[k];
                    float v  = fmaf(d, d, m);
                    dgk = up;        // old D[i-1][j] is next cell's diag
                    cur[k] = v;
                    l = v;           // left for next cell
                }
                rc[r] = l;           // right column value, row r
                dl = lc[r];          // next row's first diag = D[i][tid*8]
            }
            corner = lc[BR - 1];     // D[(bi+1)*8][tid*8] for next phase

            float* w = &ex[p & 1][tid * EXW];
            #pragma unroll
            for (int r = 0; r < BR; ++r) w[r] = rc[r];
        }
        __syncthreads();
    }

    // thread 255 computed block (255,255) at p=510; cur[7] = D[2048][2048]
    if (tid == NT - 1)
        out[0] = sqrtf(cur[BC - 1]);
}

extern "C" void kernel_launch(void* const* d_in, const int* in_sizes, int n_in,
                              void* d_out, int out_size, void* d_ws, size_t ws_size,
                              hipStream_t stream)
{
    (void)in_sizes; (void)n_in; (void)out_size; (void)d_ws; (void)ws_size;
    const float* source = (const float*)d_in[0];
    const float* target = (const float*)d_in[1];
    float* out = (float*)d_out;
    dtw_kernel<<<1, NT, 0, stream>>>(source, target, out);
}

// Round 3
// 262.761 us; speedup vs baseline: 3.2250x; 1.0677x over previous
//
#include <hip/hip_runtime.h>
#include <math.h>

// DTW 2048x2048, single workgroup of 256 threads (4 waves).
// Thread = lane ln of wave wv owns 8 columns. Row-blocks of BR=4 rows.
// Left-boundary exchange: __shfl_up within a wave (no barrier);
// across the 3 wave boundaries, a 2K-deep LDS ring mailbox with one
// __syncthreads() per K=16 iterations. Wave w is skewed DELTA=63+K
// row-blocks behind wave w-1, so consumed mailbox entries are always
// at least one barrier old (race-free by construction).

#define MM 2048
#define NN 2048
#define BR 4
#define BC 8
#define NT 256
#define NB (MM / BR)               // 512 row-blocks
#define KK 16                      // barrier period (iterations)
#define DELTA (63 + KK)            // skew between adjacent waves
#define MAXSKEW (63 + 3 * DELTA)   // 300
#define NITER (NB + MAXSKEW)       // 812
#define NSP ((NITER + KK - 1) / KK) // 51 superphases
#define RING (2 * KK)              // 32 mailbox slots per boundary
#define INFV 1e30f

__launch_bounds__(NT, 1)
__global__ void dtw_kernel(const float* __restrict__ src,
                           const float* __restrict__ tgt,
                           float* __restrict__ out)
{
    __shared__ float4 s_src4[NB];      // src staged as float4 per row-block
    __shared__ float4 mbox[3][RING];   // wave-boundary right-column ring

    const int tid  = threadIdx.x;
    const int wv   = tid >> 6;
    const int ln   = tid & 63;
    const int skew = ln + wv * DELTA;

    const float4* s4 = (const float4*)src;
    for (int i = tid; i < NB; i += NT) s_src4[i] = s4[i];

    float tg[BC];
    #pragma unroll
    for (int k = 0; k < BC; ++k) tg[k] = tgt[tid * BC + k];

    // cur[] = bottom row of this thread's previous row-block (row-0 boundary = INF)
    float cur[BC];
    #pragma unroll
    for (int k = 0; k < BC; ++k) cur[k] = INFV;

    // corner = D[bi*BR][j0-1]; D[0][0]=0 for tid 0, else INF
    float corner = (tid == 0) ? 0.0f : INFV;
    // rcp = right column of my previous iteration's block (consumed by lane+1)
    float4 rcp = make_float4(INFV, INFV, INFV, INFV);

    __syncthreads();

    for (int sp = 0; sp < NSP; ++sp) {
        #pragma unroll 1
        for (int it = 0; it < KK; ++it) {
            const int n = sp * KK + it;

            // exchange (ALL lanes execute the shfl — exec-mask safety)
            float lc0 = __shfl_up(rcp.x, 1);
            float lc1 = __shfl_up(rcp.y, 1);
            float lc2 = __shfl_up(rcp.z, 1);
            float lc3 = __shfl_up(rcp.w, 1);
            if (ln == 0) {
                if (wv == 0) {
                    lc0 = lc1 = lc2 = lc3 = INFV;    // DP left edge
                } else {
                    float4 m = mbox[wv - 1][(n - KK) & (RING - 1)];
                    lc0 = m.x; lc1 = m.y; lc2 = m.z; lc3 = m.w;
                }
            }

            const int bi = n - skew;
            if (0 <= bi && bi < NB) {
                float4 sv = s_src4[bi];
                float srow[BR] = {sv.x, sv.y, sv.z, sv.w};
                float lcx[BR]  = {lc0, lc1, lc2, lc3};

                float dg[BR], lv[BR];
                dg[0] = corner;
                lv[0] = lcx[0];
                #pragma unroll
                for (int r = 1; r < BR; ++r) { dg[r] = lcx[r - 1]; lv[r] = lcx[r]; }

                // staggered (anti-diagonal) order: 4 independent chains
                #pragma unroll
                for (int s = 0; s < BR + BC - 1; ++s) {
                    #pragma unroll
                    for (int r = 0; r < BR; ++r) {
                        const int k = s - r;
                        if (0 <= k && k < BC) {
                            float up = cur[k];
                            float m  = fminf(fminf(up, lv[r]), dg[r]);
                            float d  = srow[r] - tg[k];
                            float v  = fmaf(d, d, m);
                            dg[r] = up;
                            lv[r] = v;
                            cur[k] = v;
                        }
                    }
                }

                corner = lcx[BR - 1];
                rcp = make_float4(lv[0], lv[1], lv[2], lv[3]);
                if (ln == 63 && wv < 3)
                    mbox[wv][n & (RING - 1)] = rcp;   // visible after next barrier
            }
        }
        __syncthreads();
    }

    // tid 255 computed block (NB-1, col-strip 255) at n = 811; cur[7] = D[2048][2048]
    if (tid == NT - 1) out[0] = sqrtf(cur[BC - 1]);
}

extern "C" void kernel_launch(void* const* d_in, const int* in_sizes, int n_in,
                              void* d_out, int out_size, void* d_ws, size_t ws_size,
                              hipStream_t stream)
{
    (void)in_sizes; (void)n_in; (void)out_size; (void)d_ws; (void)ws_size;
    const float* source = (const float*)d_in[0];
    const float* target = (const float*)d_in[1];
    float* out = (float*)d_out;
    dtw_kernel<<<1, NT, 0, stream>>>(source, target, out);
}